// Round 4
// baseline (16.492 us; speedup 1.0000x reference)
//
#include <hip/hip_runtime.h>

#define DIM   1024
#define SEQ_  2048
#define NBAT  4
// 8192 rows total; 4 waves/block, 2 rows/wave -> 1024 blocks (4/CU, 16 waves/CU)

__global__ __launch_bounds__(256) void verse_embed_ln_kernel(
    const int*   __restrict__ token_ids,    // [B,S]
    const int*   __restrict__ verse_pos,    // [B,S]
    const int*   __restrict__ book_types,   // [B,S]
    const float* __restrict__ emb_table,    // [VOCAB,D]
    const float* __restrict__ book_table,   // [4,D]
    const float* __restrict__ gamma,        // [D]
    const float* __restrict__ beta,         // [D]
    float*       __restrict__ out)          // [B,S,D]
{
    __shared__ float4 bookLDS[1024];        // [type][chunk][lane] = 16 KB

    const int t    = threadIdx.x;
    const int wid  = t >> 6;
    const int lane = t & 63;
    const int base = ((blockIdx.x << 2) + wid) << 1;   // first of 2 rows

    // ---- one-time per block: stage book_table (16 KB) into LDS ----
    const float4* __restrict__ bt4 = reinterpret_cast<const float4*>(book_table);
    #pragma unroll
    for (int k = 0; k < 4; ++k)
        bookLDS[k * 256 + t] = bt4[k * 256 + t];

    // ---- per-row scalar metadata for both rows (broadcast loads) ----
    const int tok0 = token_ids[base],   tok1 = token_ids[base + 1];
    const int bt0  = book_types[base],  bt1  = book_types[base + 1];
    const int v0   = verse_pos[base],   v1   = verse_pos[base + 1];
    const int s0   = base & (SEQ_ - 1);                 // base is even -> s of row1 != 0
    const int vp0  = (s0 == 0) ? -1 : verse_pos[base - 1];
    const float w0 = (v0 != 0 && v0 != vp0) ? 1.2f : 1.0f;
    const float w1 = (v1 != 0 && v1 != v0)  ? 1.2f : 1.0f;

    // ---- issue all 8 embedding gathers up front (max MLP) ----
    const float4* __restrict__ er0 = reinterpret_cast<const float4*>(emb_table) + (size_t)tok0 * 256;
    const float4* __restrict__ er1 = reinterpret_cast<const float4*>(emb_table) + (size_t)tok1 * 256;
    float4 e[2][4];
    #pragma unroll
    for (int c = 0; c < 4; ++c) e[0][c] = er0[c * 64 + lane];
    #pragma unroll
    for (int c = 0; c < 4; ++c) e[1][c] = er1[c * 64 + lane];

    // ---- gamma/beta once per wave into registers ----
    const float4* __restrict__ g4 = reinterpret_cast<const float4*>(gamma);
    const float4* __restrict__ b4 = reinterpret_cast<const float4*>(beta);
    float4 g[4], b[4];
    #pragma unroll
    for (int c = 0; c < 4; ++c) { g[c] = g4[c * 64 + lane]; b[c] = b4[c * 64 + lane]; }

    // frequencies: f(d)=10000^(-d/1024); f(d+2)=f(d)*K2; f(d+256)=f(d)*0.1
    const float C2 = -13.287712379549449f / 1024.0f;   // -log2(10000)/D
    const float K2 = 0.9821718931198913f;              // 10000^(-1/512)
    const int   dl = lane << 2;
    const float fb0 = exp2f(C2 * (float)dl);
    const float SQD = 32.0f;

    __syncthreads();                                   // bookLDS ready

    #pragma unroll
    for (int r = 0; r < 2; ++r) {
        const int row = base + r;
        const float sf = (float)(row & (SEQ_ - 1));
        const float w  = r ? w1 : w0;
        const int  bt  = r ? bt1 : bt0;
        const float4* __restrict__ bkl = &bookLDS[bt * 256];

        float4 x[4];
        float sum = 0.0f, sq = 0.0f;
        float fb = fb0;
        #pragma unroll
        for (int c = 0; c < 4; ++c) {
            const float a0 = sf * fb;
            const float a1 = sf * (fb * K2);
            const float sn0 = __sinf(a0), cs0 = __cosf(a0);
            const float sn1 = __sinf(a1), cs1 = __cosf(a1);
            fb *= 0.1f;
            const float4 bk = bkl[c * 64 + lane];
            x[c].x = e[r][c].x * SQD + sn0 * w + bk.x;
            x[c].y = e[r][c].y * SQD + cs0 * w + bk.y;
            x[c].z = e[r][c].z * SQD + sn1 * w + bk.z;
            x[c].w = e[r][c].w * SQD + cs1 * w + bk.w;
            sum += (x[c].x + x[c].y) + (x[c].z + x[c].w);
            sq  += (x[c].x * x[c].x + x[c].y * x[c].y) + (x[c].z * x[c].z + x[c].w * x[c].w);
        }

        #pragma unroll
        for (int off = 32; off >= 1; off >>= 1) {
            sum += __shfl_xor(sum, off, 64);
            sq  += __shfl_xor(sq,  off, 64);
        }
        const float mean = sum * (1.0f / (float)DIM);
        const float var  = sq * (1.0f / (float)DIM) - mean * mean;
        const float rstd = rsqrtf(var + 1e-5f);

        float4* __restrict__ orow = reinterpret_cast<float4*>(out) + (size_t)row * 256;
        #pragma unroll
        for (int c = 0; c < 4; ++c) {
            float4 o;
            o.x = (x[c].x - mean) * rstd * g[c].x + b[c].x;
            o.y = (x[c].y - mean) * rstd * g[c].y + b[c].y;
            o.z = (x[c].z - mean) * rstd * g[c].z + b[c].z;
            o.w = (x[c].w - mean) * rstd * g[c].w + b[c].w;
            orow[c * 64 + lane] = o;
        }
    }
}

extern "C" void kernel_launch(void* const* d_in, const int* in_sizes, int n_in,
                              void* d_out, int out_size, void* d_ws, size_t ws_size,
                              hipStream_t stream) {
    const int*   token_ids  = (const int*)d_in[0];
    const int*   verse_pos  = (const int*)d_in[1];
    const int*   book_types = (const int*)d_in[2];
    const float* emb_table  = (const float*)d_in[3];
    const float* book_table = (const float*)d_in[4];
    const float* ln_gamma   = (const float*)d_in[5];
    const float* ln_beta    = (const float*)d_in[6];
    float* out = (float*)d_out;

    dim3 grid((NBAT * SEQ_) / 8);   // 4 waves/block * 2 rows/wave
    dim3 block(256);
    verse_embed_ln_kernel<<<grid, block, 0, stream>>>(
        token_ids, verse_pos, book_types, emb_table, book_table,
        ln_gamma, ln_beta, out);
}